// Round 1
// baseline (292.630 us; speedup 1.0000x reference)
//
#include <hip/hip_runtime.h>

// Problem constants (match reference)
#define BB 8
#define CC 3
#define HH 1024
#define WW 1024
#define NS 15728   // int(1024*1024*0.015)

// Gaussian 5-tap, sigma=1.5, normalized (double-precision derived)
#define G0 0.1200784f
#define G1 0.2338808f
#define G2 0.2920816f

// ---------------------------------------------------------------------------
// Kernel 1: scatter snow boxes into a per-batch bitmask (1 bit / pixel).
// mbits layout: [B][H][W/32] uint32 -> 32 words per image row.
// ---------------------------------------------------------------------------
__global__ __launch_bounds__(256) void snow_mask_kernel(
    const int* __restrict__ ys, const int* __restrict__ xs,
    const int* __restrict__ rs, unsigned int* __restrict__ mbits) {
  int idx = blockIdx.x * 256 + threadIdx.x;
  if (idx >= BB * NS) return;
  int b = idx / NS;
  int y = ys[idx];
  int x = xs[idx];
  int r = rs[idx] + 1;  // radius in {1,2,3}
  int x0 = max(x - r, 0), x1 = min(x + r, WW - 1);
  int y0 = max(y - r, 0), y1 = min(y + r, HH - 1);
  int w0 = x0 >> 5, w1 = x1 >> 5;
  unsigned int m0 = 0xFFFFFFFFu << (x0 & 31);
  unsigned int m1 = 0xFFFFFFFFu >> (31 - (x1 & 31));
  for (int py = y0; py <= y1; ++py) {
    unsigned int* rowp = mbits + ((unsigned)(b * HH + py) << 5);
    if (w0 == w1) {
      atomicOr(&rowp[w0], m0 & m1);
    } else {
      atomicOr(&rowp[w0], m0);
      atomicOr(&rowp[w1], m1);
    }
  }
}

// ---------------------------------------------------------------------------
// Kernel 2: masked-fill (0.95) + separable 5x5 Gaussian + clip, fused.
// One 64x64 output tile per (b,c) per block; 256 threads = 64x4.
// LDS: raw masked tile with 2-px halo (68x68), then horizontal-pass buffer.
// ---------------------------------------------------------------------------
__global__ __launch_bounds__(256) void snow_blur_kernel(
    const float* __restrict__ x, const unsigned int* __restrict__ mbits,
    float* __restrict__ out) {
  __shared__ float tile[68][72];  // +4 pad cols (stride 72 floats)
  __shared__ float hbuf[68][64];

  const int bz = blockIdx.z;        // b*CC + c
  const int b = bz / CC;
  const int gx0 = blockIdx.x * 64 - 2;  // image col of tile col 0
  const int gy0 = blockIdx.y * 64 - 2;  // image row of tile row 0
  const int tid = threadIdx.x;
  const int tx = tid & 63;
  const int ty = tid >> 6;          // 0..3 (wave index)
  const float* __restrict__ xp = x + (size_t)bz * (HH * WW);

  // ---- load 68x68 masked tile (zero-padded outside image) ----
  for (int rr = ty * 17; rr < ty * 17 + 17; ++rr) {
    int gy = gy0 + rr;
    bool yok = (gy >= 0) && (gy < HH);
    int gys = yok ? gy : 0;
    const unsigned int* mrow = mbits + ((unsigned)(b * HH + gys) << 5);
    const float* xrow = xp + (size_t)gys * WW;
    {
      int gx = gx0 + tx;
      float v = 0.f;
      if (yok && gx >= 0 && gx < WW) {
        v = xrow[gx];
        if ((mrow[gx >> 5] >> (gx & 31)) & 1u) v = 0.95f;
      }
      tile[rr][tx] = v;
    }
    if (tx < 4) {
      int cc = 64 + tx;
      int gx = gx0 + cc;
      float v = 0.f;
      if (yok && gx >= 0 && gx < WW) {
        v = xrow[gx];
        if ((mrow[gx >> 5] >> (gx & 31)) & 1u) v = 0.95f;
      }
      tile[rr][cc] = v;
    }
  }
  __syncthreads();

  // ---- horizontal 5-tap: output col c uses tile cols c..c+4 ----
  for (int rr = ty * 17; rr < ty * 17 + 17; ++rr) {
    float s = G0 * (tile[rr][tx] + tile[rr][tx + 4]) +
              G1 * (tile[rr][tx + 1] + tile[rr][tx + 3]) +
              G2 * tile[rr][tx + 2];
    hbuf[rr][tx] = s;
  }
  __syncthreads();

  // ---- vertical 5-tap, register sliding window, 16 rows/thread ----
  const int rbase = ty * 16;  // output row block within tile
  float a0 = hbuf[rbase + 0][tx];
  float a1 = hbuf[rbase + 1][tx];
  float a2 = hbuf[rbase + 2][tx];
  float a3 = hbuf[rbase + 3][tx];
  float a4 = hbuf[rbase + 4][tx];
  size_t obase = (size_t)bz * (HH * WW) +
                 (size_t)(blockIdx.y * 64 + rbase) * WW +
                 (size_t)(blockIdx.x * 64 + tx);
  for (int k = 0; k < 16; ++k) {
    float s = G0 * (a0 + a4) + G1 * (a1 + a3) + G2 * a2;
    s = fminf(fmaxf(s, 0.f), 1.f);
    out[obase + (size_t)k * WW] = s;
    a0 = a1; a1 = a2; a2 = a3; a3 = a4;
    if (k < 15) a4 = hbuf[rbase + k + 5][tx];
  }
}

// ---------------------------------------------------------------------------
extern "C" void kernel_launch(void* const* d_in, const int* in_sizes, int n_in,
                              void* d_out, int out_size, void* d_ws, size_t ws_size,
                              hipStream_t stream) {
  const float* x = (const float*)d_in[0];
  const int* ys = (const int*)d_in[1];
  const int* xs = (const int*)d_in[2];
  const int* rs = (const int*)d_in[3];
  float* out = (float*)d_out;

  unsigned int* mbits = (unsigned int*)d_ws;  // needs B*H*W/8 = 1 MiB
  hipMemsetAsync(mbits, 0, (size_t)BB * HH * WW / 8, stream);

  int nspot = BB * NS;
  snow_mask_kernel<<<(nspot + 255) / 256, 256, 0, stream>>>(ys, xs, rs, mbits);

  dim3 grid(WW / 64, HH / 64, BB * CC);
  snow_blur_kernel<<<grid, 256, 0, stream>>>(x, mbits, out);
}

// Round 2
// 230.871 us; speedup vs baseline: 1.2675x; 1.2675x over previous
//
#include <hip/hip_runtime.h>

// Problem constants (match reference)
#define BB 8
#define CC 3
#define HH 1024
#define WW 1024
#define NS 15728   // int(1024*1024*0.015)

// Gaussian 5-tap, sigma=1.5, normalized (double-precision derived)
#define G0 0.1200784f
#define G1 0.2338808f
#define G2 0.2920816f

// ---------------------------------------------------------------------------
// Kernel 1: scatter snow boxes into a per-batch bitmask (1 bit / pixel).
// mbits layout: [B][H][W/32] uint32 -> 32 words per image row.
// Grid: (ceil(NS/256), BB) so batch index needs no division.
// ---------------------------------------------------------------------------
__global__ __launch_bounds__(256) void snow_mask_kernel(
    const int* __restrict__ ys, const int* __restrict__ xs,
    const int* __restrict__ rs, unsigned int* __restrict__ mbits) {
  int s = blockIdx.x * 256 + threadIdx.x;
  if (s >= NS) return;
  int b = blockIdx.y;
  int idx = b * NS + s;
  int y = ys[idx];
  int x = xs[idx];
  int r = rs[idx] + 1;  // radius in {1,2,3}
  int x0 = max(x - r, 0), x1 = min(x + r, WW - 1);
  int y0 = max(y - r, 0), y1 = min(y + r, HH - 1);
  int w0 = x0 >> 5, w1 = x1 >> 5;
  unsigned int m0 = 0xFFFFFFFFu << (x0 & 31);
  unsigned int m1 = 0xFFFFFFFFu >> (31 - (x1 & 31));
  for (int py = y0; py <= y1; ++py) {
    unsigned int* rowp = mbits + ((unsigned)(b * HH + py) << 5);
    if (w0 == w1) {
      atomicOr(&rowp[w0], m0 & m1);
    } else {
      atomicOr(&rowp[w0], m0);
      atomicOr(&rowp[w1], m1);
    }
  }
}

// ---------------------------------------------------------------------------
// Kernel 2: masked-fill (0.95) + separable 5x5 Gaussian + clip, fused.
// 64x64 output tile per (b,c) per block; 256 threads.
// LDS: ONLY the raw masked tile 68 rows x 72 cols (19584 B -> 8 blocks/CU).
// Horizontal pass recomputed from LDS inside the vertical sliding window
// (VALU/LDS are idle; occupancy is the scarce resource).
// Tile col 0 = image col bx*64-4 (16B aligned -> float4 loads).
// Tile row 0 = image row by*64-2.
// ---------------------------------------------------------------------------
__device__ __forceinline__ float hpass5(const float* row, int tx) {
  // output col tx -> tile center col tx+4, taps tx+2..tx+6
  return G0 * (row[tx + 2] + row[tx + 6]) +
         G1 * (row[tx + 3] + row[tx + 5]) +
         G2 * row[tx + 4];
}

__global__ __launch_bounds__(256) void snow_blur_kernel(
    const float* __restrict__ x, const unsigned int* __restrict__ mbits,
    float* __restrict__ out) {
  __shared__ float tile[68][72];

  const int bz = blockIdx.z;        // b*CC + c
  const int b = bz / CC;
  const int bx = blockIdx.x, by = blockIdx.y;
  const int tid = threadIdx.x;
  const float* __restrict__ xp = x + (size_t)bz * (HH * WW);
  const unsigned int* __restrict__ mb = mbits + ((unsigned)(b * HH) << 5);

  const int gxbase = bx * 64 - 4;   // image col of tile col 0 (16B aligned)
  const int gybase = by * 64 - 2;   // image row of tile row 0

  const bool interior = (bx > 0) & (bx < 15) & (by > 0) & (by < 15);
  if (interior) {
    // 68 rows x 18 float4 = 1224 vector loads, branch-free
#pragma unroll
    for (int k = 0; k < 5; ++k) {
      int i = tid + k * 256;
      if (i < 1224) {
        int r = i / 18;
        int c4 = i - r * 18;
        int gy = gybase + r;
        int gx = gxbase + c4 * 4;
        float4 v = *(const float4*)(xp + (size_t)gy * WW + gx);
        unsigned int mword = mb[(gy << 5) + (gx >> 5)];
        unsigned int bits = (mword >> (gx & 31)) & 0xFu;
        if (bits & 1u) v.x = 0.95f;
        if (bits & 2u) v.y = 0.95f;
        if (bits & 4u) v.z = 0.95f;
        if (bits & 8u) v.w = 0.95f;
        *(float4*)&tile[r][c4 * 4] = v;
      }
    }
  } else {
    // edge blocks: scalar bounds-checked (zero padding outside image)
    for (int i = tid; i < 68 * 72; i += 256) {
      int r = i / 72;
      int c = i - r * 72;
      int gy = gybase + r;
      int gx = gxbase + c;
      float v = 0.f;
      if (gy >= 0 && gy < HH && gx >= 0 && gx < WW) {
        v = xp[(size_t)gy * WW + gx];
        if ((mb[(gy << 5) + (gx >> 5)] >> (gx & 31)) & 1u) v = 0.95f;
      }
      tile[r][c] = v;
    }
  }
  __syncthreads();

  // vertical 5-tap, register sliding window, 16 rows/thread;
  // horizontal 5-tap recomputed from LDS per row.
  const int tx = tid & 63;
  const int ty = tid >> 6;
  const int rbase = ty * 16;   // first output row (tile row rbase+2 center)

  float h0 = hpass5(tile[rbase + 0], tx);
  float h1 = hpass5(tile[rbase + 1], tx);
  float h2 = hpass5(tile[rbase + 2], tx);
  float h3 = hpass5(tile[rbase + 3], tx);
  float h4 = hpass5(tile[rbase + 4], tx);

  size_t obase = (size_t)bz * (HH * WW) +
                 (size_t)(by * 64 + rbase) * WW +
                 (size_t)(bx * 64 + tx);
#pragma unroll
  for (int k = 0; k < 16; ++k) {
    float s = G0 * (h0 + h4) + G1 * (h1 + h3) + G2 * h2;
    s = fminf(fmaxf(s, 0.f), 1.f);
    out[obase + (size_t)k * WW] = s;
    h0 = h1; h1 = h2; h2 = h3; h3 = h4;
    if (k < 15) h4 = hpass5(tile[rbase + k + 5], tx);
  }
}

// ---------------------------------------------------------------------------
extern "C" void kernel_launch(void* const* d_in, const int* in_sizes, int n_in,
                              void* d_out, int out_size, void* d_ws, size_t ws_size,
                              hipStream_t stream) {
  const float* x = (const float*)d_in[0];
  const int* ys = (const int*)d_in[1];
  const int* xs = (const int*)d_in[2];
  const int* rs = (const int*)d_in[3];
  float* out = (float*)d_out;

  unsigned int* mbits = (unsigned int*)d_ws;  // B*H*W/8 = 1 MiB
  hipMemsetAsync(mbits, 0, (size_t)BB * HH * WW / 8, stream);

  dim3 mgrid((NS + 255) / 256, BB);
  snow_mask_kernel<<<mgrid, 256, 0, stream>>>(ys, xs, rs, mbits);

  dim3 grid(WW / 64, HH / 64, BB * CC);
  snow_blur_kernel<<<grid, 256, 0, stream>>>(x, mbits, out);
}

// Round 3
// 210.153 us; speedup vs baseline: 1.3925x; 1.0986x over previous
//
#include <hip/hip_runtime.h>

// Problem constants (match reference)
#define BB 8
#define CC 3
#define HH 1024
#define WW 1024
#define NS 15728   // int(1024*1024*0.015)

// Gaussian 5-tap, sigma=1.5, normalized
#define G0 0.1200784f
#define G1 0.2338808f
#define G2 0.2920816f

// ---------------------------------------------------------------------------
// Kernel 1: scatter snow boxes into a per-batch bitmask (1 bit / pixel).
// mbits layout: [B][H][W/32] uint32 -> 32 words per image row.
// ---------------------------------------------------------------------------
__global__ __launch_bounds__(256) void snow_mask_kernel(
    const int* __restrict__ ys, const int* __restrict__ xs,
    const int* __restrict__ rs, unsigned int* __restrict__ mbits) {
  int s = blockIdx.x * 256 + threadIdx.x;
  if (s >= NS) return;
  int b = blockIdx.y;
  int idx = b * NS + s;
  int y = ys[idx];
  int x = xs[idx];
  int r = rs[idx] + 1;  // radius in {1,2,3}
  int x0 = max(x - r, 0), x1 = min(x + r, WW - 1);
  int y0 = max(y - r, 0), y1 = min(y + r, HH - 1);
  int w0 = x0 >> 5, w1 = x1 >> 5;
  unsigned int m0 = 0xFFFFFFFFu << (x0 & 31);
  unsigned int m1 = 0xFFFFFFFFu >> (31 - (x1 & 31));
  for (int py = y0; py <= y1; ++py) {
    unsigned int* rowp = mbits + ((unsigned)(b * HH + py) << 5);
    if (w0 == w1) {
      atomicOr(&rowp[w0], m0 & m1);
    } else {
      atomicOr(&rowp[w0], m0);
      atomicOr(&rowp[w1], m1);
    }
  }
}

// ---------------------------------------------------------------------------
// Kernel 2: masked-fill (0.95) + separable 5x5 Gaussian + clip, fused.
// Output tile 128x64 per block, 256 threads, one (b,c) per blockIdx.z.
// LDS: raw masked tile 68 rows x 140-float stride (38080 B -> 4 blocks/CU).
// Load phase: branch-free (clamped coords + OOB zero), 10 independent
//   float4 loads per thread -> high MLP. No interior/edge path split.
// Compute: each thread = 4 cols (float4) x 8 rows; horizontal 5-tap from
//   3 wide LDS reads per row (vs 20 scalar b32), vertical sliding window.
// ---------------------------------------------------------------------------
#define TS 140           // LDS row stride in floats
#define NLOAD 2312       // 68 rows * 34 float4

__global__ __launch_bounds__(256, 4) void snow_blur_kernel(
    const float* __restrict__ x, const unsigned int* __restrict__ mbits,
    float* __restrict__ out) {
  __shared__ float tile[68 * TS];

  const int bz = blockIdx.z;        // b*CC + c
  const int b = bz / CC;
  const int bx = blockIdx.x, by = blockIdx.y;
  const int tid = threadIdx.x;
  const float* __restrict__ xp = x + (size_t)bz * (HH * WW);
  const unsigned int* __restrict__ mb = mbits + ((unsigned)(b * HH) << 5);

  const int gxbase = bx * 128 - 4;  // image col of tile col 0 (16B aligned)
  const int gybase = by * 64 - 2;   // image row of tile row 0

  // ---- load phase: 10 slots/thread, all loads independent ----
  float4 v[10];
  unsigned int bits[10];
  int lidx[10];
#pragma unroll
  for (int k = 0; k < 10; ++k) {
    int i = tid + k * 256;
    i = i < (NLOAD - 1) ? i : (NLOAD - 1);   // clamp, no branch
    int r = i / 34;
    int c4 = i - r * 34;
    int gy = gybase + r;
    int gx = gxbase + c4 * 4;
    int gyc = min(max(gy, 0), HH - 1);
    int gxc = min(max(gx, 0), WW - 4);       // f4 segments fully in or out
    v[k] = *(const float4*)(xp + (size_t)gyc * WW + gxc);
    unsigned int bm = (mb[(gyc << 5) + (gxc >> 5)] >> (gxc & 31)) & 0xFu;
    if ((gy != gyc) | (gx != gxc)) bm = 16u; // OOB sentinel -> zero vector
    bits[k] = bm;
    lidx[k] = r * TS + c4 * 4;
  }
#pragma unroll
  for (int k = 0; k < 10; ++k) {
    float4 t = v[k];
    unsigned int bm = bits[k];
    if (bm & 1u) t.x = 0.95f;
    if (bm & 2u) t.y = 0.95f;
    if (bm & 4u) t.z = 0.95f;
    if (bm & 8u) t.w = 0.95f;
    if (bm & 16u) { t.x = 0.f; t.y = 0.f; t.z = 0.f; t.w = 0.f; }
    *(float4*)&tile[lidx[k]] = t;
  }
  __syncthreads();

  // ---- compute phase ----
  const int c = tid & 31;          // col group: output cols 4c..4c+3
  const int ty = tid >> 5;         // 0..7: output rows 8ty..8ty+7
  const float* trow = tile + (ty * 8) * TS + c * 4;

  // horizontal 5-tap for 4 cols from 10 contiguous tile floats (wide reads)
  auto hrow = [&](int j, float4& h) {
    const float* p = trow + j * TS;
    float4 A = *(const float4*)(p);       // cols 4c..4c+3
    float4 Bv = *(const float4*)(p + 4);  // cols 4c+4..4c+7
    float2 Cv = *(const float2*)(p + 8);  // cols 4c+8,4c+9
    h.x = G0 * (A.z + Bv.z) + G1 * (A.w + Bv.y) + G2 * Bv.x;
    h.y = G0 * (A.w + Bv.w) + G1 * (Bv.x + Bv.z) + G2 * Bv.y;
    h.z = G0 * (Bv.x + Cv.x) + G1 * (Bv.y + Bv.w) + G2 * Bv.z;
    h.w = G0 * (Bv.y + Cv.y) + G1 * (Bv.z + Cv.x) + G2 * Bv.w;
  };

  float4 h0, h1, h2, h3, h4;
  hrow(0, h0); hrow(1, h1); hrow(2, h2); hrow(3, h3); hrow(4, h4);

  float* op = out + (size_t)bz * (HH * WW) +
              (size_t)(by * 64 + ty * 8) * WW + (bx * 128 + c * 4);
#pragma unroll
  for (int k = 0; k < 8; ++k) {
    float4 s;
    s.x = G0 * (h0.x + h4.x) + G1 * (h1.x + h3.x) + G2 * h2.x;
    s.y = G0 * (h0.y + h4.y) + G1 * (h1.y + h3.y) + G2 * h2.y;
    s.z = G0 * (h0.z + h4.z) + G1 * (h1.z + h3.z) + G2 * h2.z;
    s.w = G0 * (h0.w + h4.w) + G1 * (h1.w + h3.w) + G2 * h2.w;
    s.x = fminf(fmaxf(s.x, 0.f), 1.f);
    s.y = fminf(fmaxf(s.y, 0.f), 1.f);
    s.z = fminf(fmaxf(s.z, 0.f), 1.f);
    s.w = fminf(fmaxf(s.w, 0.f), 1.f);
    *(float4*)op = s;
    op += WW;
    h0 = h1; h1 = h2; h2 = h3; h3 = h4;
    if (k < 7) hrow(k + 5, h4);
  }
}

// ---------------------------------------------------------------------------
extern "C" void kernel_launch(void* const* d_in, const int* in_sizes, int n_in,
                              void* d_out, int out_size, void* d_ws, size_t ws_size,
                              hipStream_t stream) {
  const float* x = (const float*)d_in[0];
  const int* ys = (const int*)d_in[1];
  const int* xs = (const int*)d_in[2];
  const int* rs = (const int*)d_in[3];
  float* out = (float*)d_out;

  unsigned int* mbits = (unsigned int*)d_ws;  // B*H*W/8 = 1 MiB
  hipMemsetAsync(mbits, 0, (size_t)BB * HH * WW / 8, stream);

  dim3 mgrid((NS + 255) / 256, BB);
  snow_mask_kernel<<<mgrid, 256, 0, stream>>>(ys, xs, rs, mbits);

  dim3 grid(WW / 128, HH / 64, BB * CC);
  snow_blur_kernel<<<grid, 256, 0, stream>>>(x, mbits, out);
}